// Round 3
// baseline (754.600 us; speedup 1.0000x reference)
//
#include <hip/hip_runtime.h>

#define NWIN 49
#define CDIM 128
#define SCALEQ 0.17677669529663687f

typedef _Float16 half8 __attribute__((ext_vector_type(8)));
typedef _Float16 half4v __attribute__((ext_vector_type(4)));
typedef _Float16 half2v __attribute__((ext_vector_type(2)));
typedef float f32x4 __attribute__((ext_vector_type(4)));

// strides in halves (f16 elements)
#define XL_STR 136   // x / O tile row stride (272 B)
#define QK_STR 40    // Q,K row stride (80 B)
#define P_STR  72    // P row stride (144 B)
#define VT_STR 72    // V^T row stride (144 B) — must be >= 64 cols + pad!

#define XBUF_H   (NWIN * XL_STR)          // 6664 halves per x buffer
#define PRIV0_H  (2 * XBUF_H)             // privates start after 2 x buffers
#define K_OFF_H  (NWIN * QK_STR)          // 1960: K after Q
#define VT_OFF_H (2 * NWIN * QK_STR)      // 3920: VT after Q|K (P overlays Q|K: 49*72=3528 <= 3920)
#define PRIV_H   (VT_OFF_H + 32 * VT_STR) // 3920 + 2304 = 6224 halves per wave
#define SMEM_H   (PRIV0_H + 4 * PRIV_H)   // 38224 halves = 76448 B -> 2 blocks/CU

__global__ __launch_bounds__(256, 2)
void lwa_fused(const float* __restrict__ x,
               const float* __restrict__ w_qkv,
               const float* __restrict__ b_qkv,
               const float* __restrict__ w_proj,
               const float* __restrict__ b_proj,
               const float* __restrict__ bias_table,
               const int* __restrict__ rel_index,
               float* __restrict__ out,
               int nwin_total, int wpb)
{
    __shared__ __align__(16) _Float16 smem[SMEM_H];
    const int tid  = threadIdx.x;
    const int w    = tid >> 6;       // wave = head
    const int lane = tid & 63;
    const int lo   = lane & 15;
    const int hi   = lane >> 4;

    _Float16* const Qw  = smem + PRIV0_H + w * PRIV_H;           // rows 0..48, stride 40
    _Float16* const Kw  = Qw + K_OFF_H;                          // rows 0..48, stride 40
    _Float16* const Pl  = Qw;                                    // overlay: 49 x 72
    _Float16* const VTl = Qw + VT_OFF_H;                         // 32 x 72 (cols 0..63 used)

    // ---------- per-block setup: weight B-fragments + bias into registers ----------
    half8 wb1[6][4];
    float bq[6];
#pragma unroll
    for (int tn = 0; tn < 6; ++tn) {
        int base = (tn < 2) ? (w * 32 + tn * 16)
                 : (tn < 4) ? (128 + w * 32 + (tn - 2) * 16)
                            : (256 + w * 32 + (tn - 4) * 16);
        int n = base + lo;
        bq[tn] = b_qkv[n];
#pragma unroll
        for (int kk = 0; kk < 4; ++kk) {
            const float* p = w_qkv + (size_t)n * CDIM + kk * 32 + hi * 8;
            float4 u0 = *reinterpret_cast<const float4*>(p);
            float4 u1 = *reinterpret_cast<const float4*>(p + 4);
            half8 h;
            h[0] = (_Float16)u0.x; h[1] = (_Float16)u0.y; h[2] = (_Float16)u0.z; h[3] = (_Float16)u0.w;
            h[4] = (_Float16)u1.x; h[5] = (_Float16)u1.y; h[6] = (_Float16)u1.z; h[7] = (_Float16)u1.w;
            wb1[tn][kk] = h;
        }
    }
    half8 wb3[2][4];
    float bp[2];
#pragma unroll
    for (int tn = 0; tn < 2; ++tn) {
        int n = w * 32 + tn * 16 + lo;
        bp[tn] = b_proj[n];
#pragma unroll
        for (int kk = 0; kk < 4; ++kk) {
            const float* p = w_proj + (size_t)n * CDIM + kk * 32 + hi * 8;
            float4 u0 = *reinterpret_cast<const float4*>(p);
            float4 u1 = *reinterpret_cast<const float4*>(p + 4);
            half8 h;
            h[0] = (_Float16)u0.x; h[1] = (_Float16)u0.y; h[2] = (_Float16)u0.z; h[3] = (_Float16)u0.w;
            h[4] = (_Float16)u1.x; h[5] = (_Float16)u1.y; h[6] = (_Float16)u1.z; h[7] = (_Float16)u1.w;
            wb3[tn][kk] = h;
        }
    }
    // S^T tile (tmk, tnq): element (key = 16*tmk + 4*hi + j, query = 16*tnq + lo).
    // key >= 49 masked -1e4 (exp -> 0). query >= 49 columns are never stored.
    half2v biasp[4][4][2];
#pragma unroll
    for (int tmk = 0; tmk < 4; ++tmk)
#pragma unroll
        for (int tnq = 0; tnq < 4; ++tnq)
#pragma unroll
            for (int jp = 0; jp < 2; ++jp) {
                float bv[2];
#pragma unroll
                for (int j2 = 0; j2 < 2; ++j2) {
                    int j = jp * 2 + j2;
                    int key = 16 * tmk + 4 * hi + j;
                    int q = 16 * tnq + lo;
                    if (key >= 49) bv[j2] = -1e4f;
                    else {
                        int qc = (q < 49) ? q : 48;
                        bv[j2] = bias_table[(size_t)rel_index[qc * 49 + key] * 4 + w];
                    }
                }
                half2v h; h[0] = (_Float16)bv[0]; h[1] = (_Float16)bv[1];
                biasp[tmk][tnq][jp] = h;
            }

    const f32x4 zf = {0.f, 0.f, 0.f, 0.f};
    const int r0 = tid >> 4;
    const int gcol = (tid & 15) * 8;

    int b0 = blockIdx.x * wpb;
    int b1 = b0 + wpb; if (b1 > nwin_total) b1 = nwin_total;

    // ---------- prologue: stage x[b0] -> buffer 0 ----------
    {
        const float* xs = x + (size_t)b0 * NWIN * CDIM;
#pragma unroll
        for (int p = 0; p < 4; ++p) {
            int row = r0 + p * 16;
            if (row < 49) {
                const float* sp = xs + (size_t)row * CDIM + gcol;
                float4 u0 = *reinterpret_cast<const float4*>(sp);
                float4 u1 = *reinterpret_cast<const float4*>(sp + 4);
                half8 h;
                h[0] = (_Float16)u0.x; h[1] = (_Float16)u0.y; h[2] = (_Float16)u0.z; h[3] = (_Float16)u0.w;
                h[4] = (_Float16)u1.x; h[5] = (_Float16)u1.y; h[6] = (_Float16)u1.z; h[7] = (_Float16)u1.w;
                *reinterpret_cast<half8*>(&smem[row * XL_STR + gcol]) = h;
            }
        }
    }
    __syncthreads();

    // ---------- window loop ----------
    for (int b = b0; b < b1; ++b) {
        const int par = (b - b0) & 1;
        _Float16* const xb = smem + (par ? XBUF_H : 0);   // current x; later O
        _Float16* const xn = smem + (par ? 0 : XBUF_H);   // next x
        const bool has_next = (b + 1 < b1);

        // issue next-window global loads early (latency hides under GEMM1)
        float4 st[4][2];
        if (has_next) {
            const float* xs = x + (size_t)(b + 1) * NWIN * CDIM;
#pragma unroll
            for (int p = 0; p < 4; ++p) {
                int row = r0 + p * 16;
                if (row < 49) {
                    const float* sp = xs + (size_t)row * CDIM + gcol;
                    st[p][0] = *reinterpret_cast<const float4*>(sp);
                    st[p][1] = *reinterpret_cast<const float4*>(sp + 4);
                }
            }
        }

        // ---- GEMM1: qkv for this wave's head; epilogue -> Q (scaled), K, V^T ----
#pragma unroll
        for (int tm = 0; tm < 4; ++tm) {
            int ar = 16 * tm + lo; if (ar > 48) ar = 48;
            half8 a[4];
#pragma unroll
            for (int kk = 0; kk < 4; ++kk)
                a[kk] = *reinterpret_cast<const half8*>(&xb[ar * XL_STR + kk * 32 + hi * 8]);
            f32x4 acc[6];
#pragma unroll
            for (int tn = 0; tn < 6; ++tn) acc[tn] = zf;
#pragma unroll
            for (int tn = 0; tn < 6; ++tn)
#pragma unroll
                for (int kk = 0; kk < 4; ++kk)
                    acc[tn] = __builtin_amdgcn_mfma_f32_16x16x32_f16(a[kk], wb1[tn][kk], acc[tn], 0, 0, 0);
#pragma unroll
            for (int tn = 0; tn < 4; ++tn)
#pragma unroll
                for (int j = 0; j < 4; ++j) {
                    int row = 16 * tm + 4 * hi + j;
                    if (row < 49) {
                        float v = acc[tn][j] + bq[tn];
                        if (tn < 2) Qw[row * QK_STR + tn * 16 + lo] = (_Float16)(v * SCALEQ);
                        else        Kw[row * QK_STR + (tn - 2) * 16 + lo] = (_Float16)v;
                    }
                }
#pragma unroll
            for (int tn = 4; tn < 6; ++tn) {
                half4v hv;
#pragma unroll
                for (int j = 0; j < 4; ++j) hv[j] = (_Float16)(acc[tn][j] + bq[tn]);
                *reinterpret_cast<half4v*>(&VTl[((tn - 4) * 16 + lo) * VT_STR + tm * 16 + 4 * hi]) = hv;
            }
        }

        // ---- stage writes for next window (vm-wait lands here, hidden) ----
        if (has_next) {
#pragma unroll
            for (int p = 0; p < 4; ++p) {
                int row = r0 + p * 16;
                if (row < 49) {
                    half8 h;
                    h[0] = (_Float16)st[p][0].x; h[1] = (_Float16)st[p][0].y;
                    h[2] = (_Float16)st[p][0].z; h[3] = (_Float16)st[p][0].w;
                    h[4] = (_Float16)st[p][1].x; h[5] = (_Float16)st[p][1].y;
                    h[6] = (_Float16)st[p][1].z; h[7] = (_Float16)st[p][1].w;
                    *reinterpret_cast<half8*>(&xn[row * XL_STR + gcol]) = h;
                }
            }
        }

        // ---- S^T = K Q^T (+bias), exp (no max-sub: |S|<~8), P row-major packed ----
        float inv_l[4];
        {
            half8 kf[4], qf[4];
#pragma unroll
            for (int t = 0; t < 4; ++t) {
                int kr = 16 * t + lo; if (kr > 48) kr = 48;   // keep keys finite
                kf[t] = *reinterpret_cast<const half8*>(&Kw[kr * QK_STR + hi * 8]);
                qf[t] = *reinterpret_cast<const half8*>(&Qw[(16 * t + lo) * QK_STR + hi * 8]);
            }
            float sum[4] = {0.f, 0.f, 0.f, 0.f};
#pragma unroll
            for (int tmk = 0; tmk < 4; ++tmk) {
                f32x4 s[4];
#pragma unroll
                for (int tnq = 0; tnq < 4; ++tnq)
                    s[tnq] = __builtin_amdgcn_mfma_f32_16x16x32_f16(kf[tmk], qf[tnq], zf, 0, 0, 0);
#pragma unroll
                for (int tnq = 0; tnq < 4; ++tnq) {
#pragma unroll
                    for (int jp = 0; jp < 2; ++jp) {
                        s[tnq][2 * jp]     += (float)biasp[tmk][tnq][jp][0];
                        s[tnq][2 * jp + 1] += (float)biasp[tmk][tnq][jp][1];
                    }
                    half4v hv;
#pragma unroll
                    for (int j = 0; j < 4; ++j) {
                        float p = __expf(s[tnq][j]);
                        sum[tnq] += p;
                        hv[j] = (_Float16)p;
                    }
                    int q = 16 * tnq + lo;
                    if (q < 49)
                        *reinterpret_cast<half4v*>(&Pl[q * P_STR + 16 * tmk + 4 * hi]) = hv;
                }
            }
#pragma unroll
            for (int t = 0; t < 4; ++t) {
                float s2 = sum[t];
                s2 += __shfl_xor(s2, 16);
                s2 += __shfl_xor(s2, 32);
                inv_l[t] = 1.0f / s2;
            }
        }

        // ---- O^T = V^T P^T ----
        f32x4 o[2][4];
#pragma unroll
        for (int tmc = 0; tmc < 2; ++tmc)
#pragma unroll
            for (int tnq = 0; tnq < 4; ++tnq) o[tmc][tnq] = zf;
        {
            half8 vf[2][2];
#pragma unroll
            for (int tmc = 0; tmc < 2; ++tmc)
#pragma unroll
                for (int kk = 0; kk < 2; ++kk)
                    vf[tmc][kk] = *reinterpret_cast<const half8*>(&VTl[(16 * tmc + lo) * VT_STR + kk * 32 + hi * 8]);
#pragma unroll
            for (int tnq = 0; tnq < 4; ++tnq)
#pragma unroll
                for (int kk = 0; kk < 2; ++kk) {
                    half8 pf = *reinterpret_cast<const half8*>(&Pl[(16 * tnq + lo) * P_STR + kk * 32 + hi * 8]);
#pragma unroll
                    for (int tmc = 0; tmc < 2; ++tmc)
                        o[tmc][tnq] = __builtin_amdgcn_mfma_f32_16x16x32_f16(vf[tmc][kk], pf, o[tmc][tnq], 0, 0, 0);
                }
        }

        __syncthreads(); // (1) all waves past GEMM1 reads of xb -> reuse xb as O

        // ---- O rows (token-major) packed writes, normalized ----
#pragma unroll
        for (int tnq = 0; tnq < 4; ++tnq) {
            int q = 16 * tnq + lo;
            if (q < 49) {
#pragma unroll
                for (int tmc = 0; tmc < 2; ++tmc) {
                    half4v hv;
#pragma unroll
                    for (int j = 0; j < 4; ++j)
                        hv[j] = (_Float16)(o[tmc][tnq][j] * inv_l[tnq]);
                    *reinterpret_cast<half4v*>(&xb[q * XL_STR + w * 32 + 16 * tmc + 4 * hi]) = hv;
                }
            }
        }

        __syncthreads(); // (2) O complete

        // ---- GEMM3: hoist A reads, release LDS, then MFMA + store ----
        half8 oa[4][4];
#pragma unroll
        for (int tm = 0; tm < 4; ++tm) {
            int orr = 16 * tm + lo; if (orr > 48) orr = 48;
#pragma unroll
            for (int kk = 0; kk < 4; ++kk)
                oa[tm][kk] = *reinterpret_cast<const half8*>(&xb[orr * XL_STR + kk * 32 + hi * 8]);
        }
        __syncthreads(); // (3) xb free; GEMM3 MFMAs/stores overlap next GEMM1

#pragma unroll
        for (int tm = 0; tm < 4; ++tm) {
            f32x4 g[2];
#pragma unroll
            for (int tn = 0; tn < 2; ++tn) g[tn] = zf;
#pragma unroll
            for (int tn = 0; tn < 2; ++tn)
#pragma unroll
                for (int kk = 0; kk < 4; ++kk)
                    g[tn] = __builtin_amdgcn_mfma_f32_16x16x32_f16(oa[tm][kk], wb3[tn][kk], g[tn], 0, 0, 0);
#pragma unroll
            for (int tn = 0; tn < 2; ++tn)
#pragma unroll
                for (int j = 0; j < 4; ++j) {
                    int row = 16 * tm + 4 * hi + j;
                    if (row < 49)
                        out[((size_t)b * NWIN + row) * CDIM + w * 32 + tn * 16 + lo] = g[tn][j] + bp[tn];
                }
        }
    }
}

extern "C" void kernel_launch(void* const* d_in, const int* in_sizes, int n_in,
                              void* d_out, int out_size, void* d_ws, size_t ws_size,
                              hipStream_t stream) {
    const float* x          = (const float*)d_in[0];
    // d_in[1] = q_global: unused by the reference
    const float* w_qkv      = (const float*)d_in[2];
    const float* b_qkv      = (const float*)d_in[3];
    const float* w_proj     = (const float*)d_in[4];
    const float* b_proj     = (const float*)d_in[5];
    const float* bias_table = (const float*)d_in[6];
    const int*   rel_index  = (const int*)d_in[7];

    const int nwin = in_sizes[0] / (NWIN * CDIM);   // 16384
    const int wpb = 8;
    const int nblk = (nwin + wpb - 1) / wpb;        // 2048

    lwa_fused<<<nblk, 256, 0, stream>>>(x, w_qkv, b_qkv, w_proj, b_proj,
                                        bias_table, rel_index, (float*)d_out,
                                        nwin, wpb);
}